// Round 1
// baseline (13133.948 us; speedup 1.0000x reference)
//
#include <hip/hip_runtime.h>
#include <hip/hip_bf16.h>
#include <cstdint>

#define B_  8
#define T_  512
#define H_  768
#define L_  12
#define FF_ 3072
#define M_  (B_*T_)            // 4096 token rows
#define MH_ ((size_t)M_*H_)    // 3,145,728 floats per activation buffer

enum { EPI_NONE=0, EPI_SIG=1, EPI_RELU2=2, EPI_RES=3, EPI_FFNOUT=4 };

__device__ inline float wred(float v){
  #pragma unroll
  for(int o=32;o>0;o>>=1) v += __shfl_xor(v, o, 64);
  return v;
}

// ---------------- plain LayerNorm: out = LN(in)*w + b ----------------
__global__ __launch_bounds__(256) void ln_kernel(const float* __restrict__ in,
    const float* __restrict__ w, const float* __restrict__ bb, float* __restrict__ out){
  int wave = threadIdx.x>>6, lane = threadIdx.x&63;
  int token = blockIdx.x*4 + wave;
  const float* row = in + (size_t)token*H_;
  float v[12]; float s=0.f;
  #pragma unroll
  for(int j=0;j<12;j++){ v[j]=row[lane+j*64]; s+=v[j]; }
  s = wred(s);
  float mean = s*(1.0f/H_);
  float q=0.f;
  #pragma unroll
  for(int j=0;j<12;j++){ float d=v[j]-mean; q+=d*d; }
  q = wred(q);
  float rstd = rsqrtf(q*(1.0f/H_)+1e-5f);
  float* orow = out + (size_t)token*H_;
  #pragma unroll
  for(int j=0;j<12;j++){ int d=lane+j*64; orow[d]=(v[j]-mean)*rstd*w[d]+bb[d]; }
}

// ---- LN + token-shift + lerp-mix (recomputes LN of prev token; sh=0 at t=0) ----
// xv/mv may be null (FFN path has only k and r mixes).
__global__ __launch_bounds__(256) void ln_mix_kernel(const float* __restrict__ h,
    const float* __restrict__ w, const float* __restrict__ bb,
    const float* __restrict__ mk, const float* __restrict__ mv, const float* __restrict__ mr,
    float* __restrict__ xk, float* __restrict__ xv, float* __restrict__ xr){
  int wave = threadIdx.x>>6, lane = threadIdx.x&63;
  int token = blockIdx.x*4 + wave;
  int tt = token & (T_-1);
  bool hasPrev = (tt != 0);
  const float* row  = h + (size_t)token*H_;
  const float* prow = row - H_;
  float cur[12], prv[12];
  float s=0.f, sp=0.f;
  #pragma unroll
  for(int j=0;j<12;j++){
    cur[j]=row[lane+j*64]; s+=cur[j];
    prv[j]= hasPrev ? prow[lane+j*64] : 0.f; sp+=prv[j];
  }
  s=wred(s); sp=wred(sp);
  float mean=s*(1.0f/H_), meanp=sp*(1.0f/H_);
  float q=0.f,qp=0.f;
  #pragma unroll
  for(int j=0;j<12;j++){ float d=cur[j]-mean; q+=d*d; float dp=prv[j]-meanp; qp+=dp*dp; }
  q=wred(q); qp=wred(qp);
  float rstd =rsqrtf(q *(1.0f/H_)+1e-5f);
  float rstdp=rsqrtf(qp*(1.0f/H_)+1e-5f);
  size_t base=(size_t)token*H_;
  #pragma unroll
  for(int j=0;j<12;j++){
    int d=lane+j*64;
    float hn=(cur[j]-mean)*rstd*w[d]+bb[d];
    float sh=hasPrev ? ((prv[j]-meanp)*rstdp*w[d]+bb[d]) : 0.f;
    float mkd=mk[d]; xk[base+d]=hn*mkd+sh*(1.f-mkd);
    if(xv){ float mvd=mv[d]; xv[base+d]=hn*mvd+sh*(1.f-mvd); }
    float mrd=mr[d]; xr[base+d]=hn*mrd+sh*(1.f-mrd);
  }
}

// ------------- WKV v4 stable scan; fuses receptance gate: ra = sigmoid(r)*wkv -------------
__global__ __launch_bounds__(256) void wkv_kernel(const float* __restrict__ kk,
    const float* __restrict__ vv, const float* __restrict__ rr,
    const float* __restrict__ td, const float* __restrict__ tf, float* __restrict__ ra){
  int idx = blockIdx.x*blockDim.x + threadIdx.x;      // [0, B*H)
  int b = idx / H_, hc = idx % H_;
  float w = -expf(td[hc]);
  float u = tf[hc];
  float num=0.f, den=0.f, mx=-1e38f;
  size_t base = (size_t)b*T_*H_ + hc;
  for(int t=0;t<T_;t++){
    size_t off = base + (size_t)t*H_;
    float kt = kk[off], vt = vv[off];
    float a  = kt + u;
    float mo = fmaxf(mx, a);
    float e1 = expf(mx - mo), e2 = expf(a - mo);
    float out = (e1*num + e2*vt) / (e1*den + e2);
    float ms = fmaxf(mx + w, kt);
    float f1 = expf(mx + w - ms), f2 = expf(kt - ms);
    num = f1*num + f2*vt;
    den = f1*den + f2;
    mx  = ms;
    ra[off] = rr[off]*out;
  }
}

// ---------------- f32 tiled GEMM, C[M,N] = epi(A[M,K] @ W[K,N]) ----------------
// 64x64 tile, 256 threads, 4x4 per thread, K-tile 16.
template<int EPI>
__global__ __launch_bounds__(256) void gemm_f32(const float* __restrict__ A,
    const float* __restrict__ W, float* __restrict__ C, int N, int K,
    const float* __restrict__ aux){
  __shared__ float As[16][68];   // [k][m], padded stride 68 (16B-aligned, conflict-light)
  __shared__ float Bs[16][68];   // [k][n]
  int tid=threadIdx.x;
  int tx=tid&15, ty=tid>>4;
  int m0=blockIdx.y*64, n0=blockIdx.x*64;
  int aRow=tid>>2, aK=(tid&3)*4;
  int bRow=tid>>4, bCol=(tid&15)*4;
  const float* Aptr = A + (size_t)(m0+aRow)*K + aK;
  const float* Wptr = W + (size_t)bRow*N + n0 + bCol;
  float acc[4][4]={};
  for(int k0=0;k0<K;k0+=16){
    float4 a4 = *(const float4*)(Aptr + k0);
    float4 b4 = *(const float4*)(Wptr + (size_t)k0*N);
    __syncthreads();
    As[aK+0][aRow]=a4.x; As[aK+1][aRow]=a4.y; As[aK+2][aRow]=a4.z; As[aK+3][aRow]=a4.w;
    *(float4*)(&Bs[bRow][bCol]) = b4;
    __syncthreads();
    #pragma unroll
    for(int kk=0;kk<16;kk++){
      float4 av=*(const float4*)(&As[kk][ty*4]);
      float4 bv=*(const float4*)(&Bs[kk][tx*4]);
      float a[4]={av.x,av.y,av.z,av.w};
      float b[4]={bv.x,bv.y,bv.z,bv.w};
      #pragma unroll
      for(int i=0;i<4;i++)
        #pragma unroll
        for(int j=0;j<4;j++)
          acc[i][j]=fmaf(a[i],b[j],acc[i][j]);
    }
  }
  #pragma unroll
  for(int i=0;i<4;i++){
    int row=m0+ty*4+i;
    float* crow = C + (size_t)row*N + n0 + tx*4;
    float r[4];
    #pragma unroll
    for(int j=0;j<4;j++) r[j]=acc[i][j];
    if(EPI==EPI_SIG){
      #pragma unroll
      for(int j=0;j<4;j++) r[j]=1.f/(1.f+expf(-r[j]));
    } else if(EPI==EPI_RELU2){
      #pragma unroll
      for(int j=0;j<4;j++){ float t=fmaxf(r[j],0.f); r[j]=t*t; }
    } else if(EPI==EPI_RES){
      float4 old=*(const float4*)crow;
      r[0]+=old.x; r[1]+=old.y; r[2]+=old.z; r[3]+=old.w;
    } else if(EPI==EPI_FFNOUT){
      float4 old=*(const float4*)crow;
      float4 au =*(const float4*)(aux + (size_t)row*N + n0 + tx*4);
      r[0]=old.x+au.x*r[0]; r[1]=old.y+au.y*r[1];
      r[2]=old.z+au.z*r[2]; r[3]=old.w+au.w*r[3];
    }
    float4 v; v.x=r[0]; v.y=r[1]; v.z=r[2]; v.w=r[3];
    *(float4*)crow = v;
  }
}

static inline void gemm_launch(int epi, const float* A, const float* W, float* C,
                               int N, int K, const float* aux, hipStream_t s){
  dim3 g(N/64, M_/64), b(256);
  switch(epi){
    case EPI_NONE:   gemm_f32<EPI_NONE>  <<<g,b,0,s>>>(A,W,C,N,K,aux); break;
    case EPI_SIG:    gemm_f32<EPI_SIG>   <<<g,b,0,s>>>(A,W,C,N,K,aux); break;
    case EPI_RELU2:  gemm_f32<EPI_RELU2> <<<g,b,0,s>>>(A,W,C,N,K,aux); break;
    case EPI_RES:    gemm_f32<EPI_RES>   <<<g,b,0,s>>>(A,W,C,N,K,aux); break;
    case EPI_FFNOUT: gemm_f32<EPI_FFNOUT><<<g,b,0,s>>>(A,W,C,N,K,aux); break;
  }
}

extern "C" void kernel_launch(void* const* d_in, const int* in_sizes, int n_in,
                              void* d_out, int out_size, void* d_ws, size_t ws_size,
                              hipStream_t stream){
  const float* x      = (const float*)d_in[0];
  const float* pre_w  = (const float*)d_in[1];
  const float* pre_b  = (const float*)d_in[2];
  const float* ln1_w  = (const float*)d_in[3];
  const float* ln1_b  = (const float*)d_in[4];
  const float* ln2_w  = (const float*)d_in[5];
  const float* ln2_b  = (const float*)d_in[6];
  const float* tdec   = (const float*)d_in[7];
  const float* tfirst = (const float*)d_in[8];
  const float* amk    = (const float*)d_in[9];
  const float* amv    = (const float*)d_in[10];
  const float* amr    = (const float*)d_in[11];
  const float* Wk     = (const float*)d_in[12];
  const float* Wv     = (const float*)d_in[13];
  const float* Wr     = (const float*)d_in[14];
  const float* Wo     = (const float*)d_in[15];
  const float* fmk    = (const float*)d_in[16];
  const float* fmr    = (const float*)d_in[17];
  const float* Fk     = (const float*)d_in[18];
  const float* Fv     = (const float*)d_in[19];
  const float* Fr     = (const float*)d_in[20];
  const float* lno_w  = (const float*)d_in[21];
  const float* lno_b  = (const float*)d_in[22];
  const float* head_w = (const float*)d_in[23];
  float* out = (float*)d_out;

  // workspace layout: 7 activation buffers + kf (4 units) = 11 * MH_ floats (~138 MB)
  float* ws = (float*)d_ws;
  float* h  = ws + 0*MH_;     // residual stream
  float* b1 = ws + 1*MH_;     // xk -> ra -> final hn
  float* b2 = ws + 2*MH_;     // xv -> xk2(ffn)
  float* b3 = ws + 3*MH_;     // xr -> xr2(ffn)
  float* b4 = ws + 4*MH_;     // k  -> rf(ffn)
  float* b5 = ws + 5*MH_;     // v
  float* b6 = ws + 6*MH_;     // r(sigmoid)
  float* kf = ws + 7*MH_;     // [M, FF] relu^2(k_ffn)

  dim3 lnG(M_/4), lnB(256);

  // block-0 pre_ln
  ln_kernel<<<lnG,lnB,0,stream>>>(x, pre_w, pre_b, h);

  for(int i=0;i<L_;i++){
    size_t oH  = (size_t)i*H_;
    size_t oHH = (size_t)i*H_*H_;
    size_t oHF = (size_t)i*H_*FF_;
    // ---- time mixing ----
    ln_mix_kernel<<<lnG,lnB,0,stream>>>(h, ln1_w+oH, ln1_b+oH, amk+oH, amv+oH, amr+oH, b1,b2,b3);
    gemm_launch(EPI_NONE, b1, Wk+oHH, b4, H_, H_, nullptr, stream);
    gemm_launch(EPI_NONE, b2, Wv+oHH, b5, H_, H_, nullptr, stream);
    gemm_launch(EPI_SIG,  b3, Wr+oHH, b6, H_, H_, nullptr, stream);
    wkv_kernel<<<dim3((B_*H_)/256),dim3(256),0,stream>>>(b4,b5,b6, tdec+oH, tfirst+oH, b1);
    gemm_launch(EPI_RES,  b1, Wo+oHH, h, H_, H_, nullptr, stream);
    // ---- channel mixing ----
    ln_mix_kernel<<<lnG,lnB,0,stream>>>(h, ln2_w+oH, ln2_b+oH, fmk+oH, nullptr, fmr+oH, b2,nullptr,b3);
    gemm_launch(EPI_RELU2, b2, Fk+oHF, kf, FF_, H_, nullptr, stream);
    gemm_launch(EPI_SIG,   b3, Fr+oHH, b4, H_, H_, nullptr, stream);
    gemm_launch(EPI_FFNOUT, kf, Fv+(size_t)i*FF_*H_, h, H_, FF_, b4, stream);
  }

  // final LN + head
  ln_kernel<<<lnG,lnB,0,stream>>>(h, lno_w, lno_b, b1);
  gemm_launch(EPI_NONE, b1, head_w, out, H_, H_, nullptr, stream);
}

// Round 2
// 4802.698 us; speedup vs baseline: 2.7347x; 2.7347x over previous
//
#include <hip/hip_runtime.h>
#include <hip/hip_bf16.h>
#include <cstdint>

#define B_  8
#define T_  512
#define H_  768
#define L_  12
#define FF_ 3072
#define M_  (B_*T_)            // 4096 token rows
#define MH_ ((size_t)M_*H_)    // 3,145,728 elements per activation buffer
#define HH_ ((size_t)H_*H_)
#define HFF_ ((size_t)H_*FF_)

enum { EPI_NONE=0, EPI_SIG=1, EPI_RELU2=2, EPI_RES=3, EPI_FFNOUT=4 };

typedef __attribute__((ext_vector_type(8))) short bf16x8;
typedef __attribute__((ext_vector_type(4))) float f32x4;

__device__ inline float wred(float v){
  #pragma unroll
  for(int o=32;o>0;o>>=1) v += __shfl_xor(v, o, 64);
  return v;
}

__device__ inline void gload_lds16(const void* g, void* l){
  __builtin_amdgcn_global_load_lds(
      (const __attribute__((address_space(1))) unsigned int*)g,
      (__attribute__((address_space(3))) unsigned int*)l, 16, 0, 0);
}

// ---------------- plain LayerNorm: out = LN(in)*w + b ----------------
template<typename OT>
__global__ __launch_bounds__(256) void ln_kernel(const float* __restrict__ in,
    const float* __restrict__ w, const float* __restrict__ bb, OT* __restrict__ out){
  int wave = threadIdx.x>>6, lane = threadIdx.x&63;
  int token = blockIdx.x*4 + wave;
  const float* row = in + (size_t)token*H_;
  float v[12]; float s=0.f;
  #pragma unroll
  for(int j=0;j<12;j++){ v[j]=row[lane+j*64]; s+=v[j]; }
  s = wred(s);
  float mean = s*(1.0f/H_);
  float q=0.f;
  #pragma unroll
  for(int j=0;j<12;j++){ float d=v[j]-mean; q+=d*d; }
  q = wred(q);
  float rstd = rsqrtf(q*(1.0f/H_)+1e-5f);
  OT* orow = out + (size_t)token*H_;
  #pragma unroll
  for(int j=0;j<12;j++){ int d=lane+j*64; orow[d]=(OT)((v[j]-mean)*rstd*w[d]+bb[d]); }
}

// ---- LN + token-shift + lerp-mix; outputs bf16 GEMM inputs. xv/mv may be null. ----
__global__ __launch_bounds__(256) void ln_mix_kernel(const float* __restrict__ h,
    const float* __restrict__ w, const float* __restrict__ bb,
    const float* __restrict__ mk, const float* __restrict__ mv, const float* __restrict__ mr,
    __hip_bfloat16* __restrict__ xk, __hip_bfloat16* __restrict__ xv, __hip_bfloat16* __restrict__ xr){
  int wave = threadIdx.x>>6, lane = threadIdx.x&63;
  int token = blockIdx.x*4 + wave;
  int tt = token & (T_-1);
  bool hasPrev = (tt != 0);
  const float* row  = h + (size_t)token*H_;
  const float* prow = row - H_;
  float cur[12], prv[12];
  float s=0.f, sp=0.f;
  #pragma unroll
  for(int j=0;j<12;j++){
    cur[j]=row[lane+j*64]; s+=cur[j];
    prv[j]= hasPrev ? prow[lane+j*64] : 0.f; sp+=prv[j];
  }
  s=wred(s); sp=wred(sp);
  float mean=s*(1.0f/H_), meanp=sp*(1.0f/H_);
  float q=0.f,qp=0.f;
  #pragma unroll
  for(int j=0;j<12;j++){ float d=cur[j]-mean; q+=d*d; float dp=prv[j]-meanp; qp+=dp*dp; }
  q=wred(q); qp=wred(qp);
  float rstd =rsqrtf(q *(1.0f/H_)+1e-5f);
  float rstdp=rsqrtf(qp*(1.0f/H_)+1e-5f);
  size_t base=(size_t)token*H_;
  #pragma unroll
  for(int j=0;j<12;j++){
    int d=lane+j*64;
    float hn=(cur[j]-mean)*rstd*w[d]+bb[d];
    float sh=hasPrev ? ((prv[j]-meanp)*rstdp*w[d]+bb[d]) : 0.f;
    float mkd=mk[d]; xk[base+d]=__float2bfloat16(hn*mkd+sh*(1.f-mkd));
    if(xv){ float mvd=mv[d]; xv[base+d]=__float2bfloat16(hn*mvd+sh*(1.f-mvd)); }
    float mrd=mr[d]; xr[base+d]=__float2bfloat16(hn*mrd+sh*(1.f-mrd));
  }
}

// ------- WKV v4 stable scan; fuses gate: ra = sigmoid(r)*wkv, output bf16 -------
__global__ __launch_bounds__(256) void wkv_kernel(const float* __restrict__ kk,
    const float* __restrict__ vv, const float* __restrict__ rr,
    const float* __restrict__ td, const float* __restrict__ tf,
    __hip_bfloat16* __restrict__ ra){
  int idx = blockIdx.x*blockDim.x + threadIdx.x;      // [0, B*H)
  int b = idx / H_, hc = idx % H_;
  float w = -__expf(td[hc]);
  float u = tf[hc];
  float num=0.f, den=0.f, mx=-1e38f;
  size_t base = (size_t)b*T_*H_ + hc;
  for(int t=0;t<T_;t++){
    size_t off = base + (size_t)t*H_;
    float kt = kk[off], vt = vv[off];
    float a  = kt + u;
    float mo = fmaxf(mx, a);
    float e1 = __expf(mx - mo), e2 = __expf(a - mo);
    float out = (e1*num + e2*vt) / (e1*den + e2);
    float ms = fmaxf(mx + w, kt);
    float f1 = __expf(mx + w - ms), f2 = __expf(kt - ms);
    num = f1*num + f2*vt;
    den = f1*den + f2;
    mx  = ms;
    ra[off] = __float2bfloat16(rr[off]*out);
  }
}

// ---- transpose+cast: src f32 [K,N] (layer-strided) -> dst bf16 [N,K] ----
__global__ __launch_bounds__(256) void trans_bf16_kernel(const float* __restrict__ src,
    __hip_bfloat16* __restrict__ dst, int K, int N){
  __shared__ float tile[32][33];
  const float* s = src + (size_t)blockIdx.z*K*N;
  __hip_bfloat16* d = dst + (size_t)blockIdx.z*K*N;
  int kb = blockIdx.y*32, nb = blockIdx.x*32;
  int tx = threadIdx.x & 31, ty = threadIdx.x >> 5;   // 32 x 8
  #pragma unroll
  for(int r=0;r<32;r+=8) tile[ty+r][tx] = s[(size_t)(kb+ty+r)*N + nb+tx];
  __syncthreads();
  #pragma unroll
  for(int r=0;r<32;r+=8) d[(size_t)(nb+ty+r)*K + kb+tx] = __float2bfloat16(tile[tx][ty+r]);
}

// ---------------- bf16 MFMA GEMM: C[M,N] = epi(A[M,K] @ Bt[N,K]^T) ----------------
// 128x128 tile, BK=64, 4 waves (2x2), 16x16x32 MFMA, global_load_lds w/ pre-swizzled
// source (XOR slot swizzle: slot c16 ^= row&7) for conflict-free ds_read_b128.
template<int EPI>
__global__ __launch_bounds__(256) void gemm_bf16(const unsigned short* __restrict__ A,
    const unsigned short* __restrict__ Bt, void* __restrict__ Cv, int N, int K,
    const float* __restrict__ aux){
  __shared__ unsigned short As[128*64];
  __shared__ unsigned short Bs[128*64];
  int tid = threadIdx.x;
  int lane = tid & 63, wave = tid >> 6;
  int wr = wave >> 1, wc = wave & 1;
  int m0 = blockIdx.y * 128, n0 = blockIdx.x * 128;

  f32x4 acc[4][4] = {};

  for(int k0=0; k0<K; k0+=64){
    __syncthreads();
    #pragma unroll
    for(int i=0;i<4;i++){
      int s = i*256 + tid;
      int row = s>>3, c16 = s&7;
      int sc = (c16 ^ (row&7))*8;
      gload_lds16(A + (size_t)(m0+row)*K + k0 + sc, &As[s*8]);
    }
    #pragma unroll
    for(int i=0;i<4;i++){
      int s = i*256 + tid;
      int row = s>>3, c16 = s&7;
      int sc = (c16 ^ (row&7))*8;
      gload_lds16(Bt + (size_t)(n0+row)*K + k0 + sc, &Bs[s*8]);
    }
    __syncthreads();
    int l15 = lane & 15, lhi = lane >> 4;
    #pragma unroll
    for(int ks=0; ks<2; ks++){
      bf16x8 af[4], bfr[4];
      #pragma unroll
      for(int m=0;m<4;m++){
        int row = wr*64 + m*16 + l15;
        int c16 = (ks*4 + lhi) ^ (row & 7);
        af[m] = *(const bf16x8*)&As[row*64 + c16*8];
      }
      #pragma unroll
      for(int n=0;n<4;n++){
        int row = wc*64 + n*16 + l15;
        int c16 = (ks*4 + lhi) ^ (row & 7);
        bfr[n] = *(const bf16x8*)&Bs[row*64 + c16*8];
      }
      #pragma unroll
      for(int m=0;m<4;m++)
        #pragma unroll
        for(int n=0;n<4;n++)
          acc[m][n] = __builtin_amdgcn_mfma_f32_16x16x32_bf16(af[m], bfr[n], acc[m][n], 0,0,0);
    }
  }
  int l15 = lane&15, lhi = lane>>4;
  #pragma unroll
  for(int m=0;m<4;m++){
    #pragma unroll
    for(int n=0;n<4;n++){
      #pragma unroll
      for(int j=0;j<4;j++){
        int row = m0 + wr*64 + m*16 + lhi*4 + j;
        int col = n0 + wc*64 + n*16 + l15;
        size_t idx = (size_t)row*N + col;
        float r = acc[m][n][j];
        if(EPI==EPI_SIG){
          ((float*)Cv)[idx] = 1.f/(1.f+__expf(-r));
        } else if(EPI==EPI_RELU2){
          float t=fmaxf(r,0.f);
          ((__hip_bfloat16*)Cv)[idx] = __float2bfloat16(t*t);
        } else if(EPI==EPI_RES){
          ((float*)Cv)[idx] += r;
        } else if(EPI==EPI_FFNOUT){
          ((float*)Cv)[idx] += aux[idx]*r;
        } else {
          ((float*)Cv)[idx] = r;
        }
      }
    }
  }
}

template<int EPI>
static void gemmL(const void* A, const void* Bt, void* C, int N, int K,
                  const float* aux, hipStream_t s){
  dim3 g(N/128, M_/128);
  gemm_bf16<EPI><<<g, 256, 0, s>>>((const unsigned short*)A, (const unsigned short*)Bt, C, N, K, aux);
}

extern "C" void kernel_launch(void* const* d_in, const int* in_sizes, int n_in,
                              void* d_out, int out_size, void* d_ws, size_t ws_size,
                              hipStream_t stream){
  const float* x      = (const float*)d_in[0];
  const float* pre_w  = (const float*)d_in[1];
  const float* pre_b  = (const float*)d_in[2];
  const float* ln1_w  = (const float*)d_in[3];
  const float* ln1_b  = (const float*)d_in[4];
  const float* ln2_w  = (const float*)d_in[5];
  const float* ln2_b  = (const float*)d_in[6];
  const float* tdec   = (const float*)d_in[7];
  const float* tfirst = (const float*)d_in[8];
  const float* amk    = (const float*)d_in[9];
  const float* amv    = (const float*)d_in[10];
  const float* amr    = (const float*)d_in[11];
  const float* Wk     = (const float*)d_in[12];
  const float* Wv     = (const float*)d_in[13];
  const float* Wr     = (const float*)d_in[14];
  const float* Wo     = (const float*)d_in[15];
  const float* fmk    = (const float*)d_in[16];
  const float* fmr    = (const float*)d_in[17];
  const float* Fk     = (const float*)d_in[18];
  const float* Fv     = (const float*)d_in[19];
  const float* Fr     = (const float*)d_in[20];
  const float* lno_w  = (const float*)d_in[21];
  const float* lno_b  = (const float*)d_in[22];
  const float* head_w = (const float*)d_in[23];
  float* out = (float*)d_out;

  // ---- workspace carve-up ----
  char* p = (char*)d_ws;
  auto alloc = [&](size_t bytes){ void* r = (void*)p; p += (bytes + 255) & ~(size_t)255; return r; };
  float* h    = (float*)alloc(MH_*4);
  float* kbuf = (float*)alloc(MH_*4);
  float* vbuf = (float*)alloc(MH_*4);
  float* rbuf = (float*)alloc(MH_*4);          // r, later rf
  __hip_bfloat16* xk_b = (__hip_bfloat16*)alloc(MH_*2);  // xk / ra / xk2 / final hn
  __hip_bfloat16* xv_b = (__hip_bfloat16*)alloc(MH_*2);
  __hip_bfloat16* xr_b = (__hip_bfloat16*)alloc(MH_*2);
  __hip_bfloat16* kf_b = (__hip_bfloat16*)alloc((size_t)M_*FF_*2);
  __hip_bfloat16* WkT  = (__hip_bfloat16*)alloc(L_*HH_*2);
  __hip_bfloat16* WvT  = (__hip_bfloat16*)alloc(L_*HH_*2);
  __hip_bfloat16* WrT  = (__hip_bfloat16*)alloc(L_*HH_*2);
  __hip_bfloat16* WoT  = (__hip_bfloat16*)alloc(L_*HH_*2);
  __hip_bfloat16* FkT  = (__hip_bfloat16*)alloc(L_*HFF_*2);
  __hip_bfloat16* FvT  = (__hip_bfloat16*)alloc(L_*HFF_*2);
  __hip_bfloat16* FrT  = (__hip_bfloat16*)alloc(L_*HH_*2);
  __hip_bfloat16* hdT  = (__hip_bfloat16*)alloc(HH_*2);

  // ---- weight transpose+cast (per call; ws is re-poisoned every launch) ----
  {
    dim3 b(256);
    trans_bf16_kernel<<<dim3(H_/32,  H_/32, L_), b, 0, stream>>>(Wk, WkT, H_, H_);
    trans_bf16_kernel<<<dim3(H_/32,  H_/32, L_), b, 0, stream>>>(Wv, WvT, H_, H_);
    trans_bf16_kernel<<<dim3(H_/32,  H_/32, L_), b, 0, stream>>>(Wr, WrT, H_, H_);
    trans_bf16_kernel<<<dim3(H_/32,  H_/32, L_), b, 0, stream>>>(Wo, WoT, H_, H_);
    trans_bf16_kernel<<<dim3(FF_/32, H_/32, L_), b, 0, stream>>>(Fk, FkT, H_, FF_);
    trans_bf16_kernel<<<dim3(H_/32, FF_/32, L_), b, 0, stream>>>(Fv, FvT, FF_, H_);
    trans_bf16_kernel<<<dim3(H_/32,  H_/32, L_), b, 0, stream>>>(Fr, FrT, H_, H_);
    trans_bf16_kernel<<<dim3(H_/32,  H_/32, 1 ), b, 0, stream>>>(head_w, hdT, H_, H_);
  }

  dim3 lnG(M_/4), lnB(256);
  ln_kernel<float><<<lnG,lnB,0,stream>>>(x, pre_w, pre_b, h);

  for(int i=0;i<L_;i++){
    size_t oH  = (size_t)i*H_;
    // ---- time mixing ----
    ln_mix_kernel<<<lnG,lnB,0,stream>>>(h, ln1_w+oH, ln1_b+oH, amk+oH, amv+oH, amr+oH,
                                        xk_b, xv_b, xr_b);
    gemmL<EPI_NONE>(xk_b, WkT + i*HH_, kbuf, H_, H_, nullptr, stream);
    gemmL<EPI_NONE>(xv_b, WvT + i*HH_, vbuf, H_, H_, nullptr, stream);
    gemmL<EPI_SIG> (xr_b, WrT + i*HH_, rbuf, H_, H_, nullptr, stream);
    wkv_kernel<<<dim3((B_*H_)/256),dim3(256),0,stream>>>(kbuf,vbuf,rbuf, tdec+oH, tfirst+oH, xk_b);
    gemmL<EPI_RES> (xk_b, WoT + i*HH_, h, H_, H_, nullptr, stream);
    // ---- channel mixing ----
    ln_mix_kernel<<<lnG,lnB,0,stream>>>(h, ln2_w+oH, ln2_b+oH, fmk+oH, nullptr, fmr+oH,
                                        xk_b, nullptr, xr_b);
    gemmL<EPI_RELU2>(xk_b, FkT + i*HFF_, kf_b, FF_, H_, nullptr, stream);
    gemmL<EPI_SIG>  (xr_b, FrT + i*HH_,  rbuf, H_, H_, nullptr, stream);
    gemmL<EPI_FFNOUT>(kf_b, FvT + i*HFF_, h, H_, FF_, rbuf, stream);
  }

  // final LN + head
  ln_kernel<__hip_bfloat16><<<lnG,lnB,0,stream>>>(h, lno_w, lno_b, xk_b);
  gemmL<EPI_NONE>(xk_b, hdT, out, H_, H_, nullptr, stream);
}